// Round 4
// baseline (284.664 us; speedup 1.0000x reference)
//
#include <hip/hip_runtime.h>

// N1=4097, N2=8192. y = x[1:].reshape(8192,4096); y[r,c] = x[r*4096+c+1]
// sum over r in [0,8191), c in [0,4095):
//   b[r,c] * (y[r,c] - prev^2)^2 ,  prev = y[r,c-1] (c>0) else y[r,4095]
// out = -a*(x[0]-mu)^2 - sum
//
// Round-4: FORCED deep MLP via inline asm. Evidence from r1-r3:
//  - L3-warm replay dispatches ran at the SAME 103us with ~0 HBM traffic
//    -> latency-bound, not BW-bound; L3-hit latency ~= HBM latency.
//  - VGPR counts (20/36/28) prove the compiler re-serialized every
//    "batched load" attempt into load->wait->fma chains (~1 load in
//    flight per wave). Little's law then gives exactly the observed
//    ~10 GB/s/CU.
// Here one asm block issues all 9 loads back-to-back (all results live,
// early-clobber), single s_waitcnt vmcnt(0) + sched_barrier(0), then
// compute. 8.25 KB per wave in flight instead of ~1 KB.

#define ROWS  8191
#define BLOCK 256

__global__ __launch_bounds__(BLOCK) void rosen_partial(
    const float* __restrict__ x, const float* __restrict__ b,
    float* __restrict__ partial)
{
    const unsigned r = blockIdx.x;
    const unsigned t = threadIdx.x;
    const size_t   e = (size_t)r * 4096u + (size_t)t * 16u;

    const float* xp = x + e;
    const float* bp = b + e;

    float4 xv0, xv1, xv2, xv3, bv0, bv1, bv2, bv3;
    float  xs;

    // 9 loads issued back-to-back; all 33 result VGPRs live simultaneously.
    asm volatile(
        "global_load_dwordx4 %0, %9, off\n\t"
        "global_load_dwordx4 %1, %9, off offset:16\n\t"
        "global_load_dwordx4 %2, %9, off offset:32\n\t"
        "global_load_dwordx4 %3, %9, off offset:48\n\t"
        "global_load_dword   %8, %9, off offset:64\n\t"
        "global_load_dwordx4 %4, %10, off\n\t"
        "global_load_dwordx4 %5, %10, off offset:16\n\t"
        "global_load_dwordx4 %6, %10, off offset:32\n\t"
        "global_load_dwordx4 %7, %10, off offset:48\n\t"
        : "=&v"(xv0), "=&v"(xv1), "=&v"(xv2), "=&v"(xv3),
          "=&v"(bv0), "=&v"(bv1), "=&v"(bv2), "=&v"(bv3), "=&v"(xs)
        : "v"(xp), "v"(bp)
        : "memory");

    // col-0 wrap (t==0 only): prev = y[r,4095]; rides with the batch above
    float wrapv = 0.0f;
    if (t == 0) wrapv = x[e + 4096];

    asm volatile("s_waitcnt vmcnt(0)" ::: "memory");
    __builtin_amdgcn_sched_barrier(0);

    float p0 = (t == 0) ? wrapv : xv0.x;
    if (t == BLOCK - 1) bv3.w = 0.0f;        // col 4095 excluded

    float d, acc;
    d = xv0.y - p0    * p0;     acc  = bv0.x * d * d;
    d = xv0.z - xv0.y * xv0.y;  acc += bv0.y * d * d;
    d = xv0.w - xv0.z * xv0.z;  acc += bv0.z * d * d;
    d = xv1.x - xv0.w * xv0.w;  acc += bv0.w * d * d;
    d = xv1.y - xv1.x * xv1.x;  acc += bv1.x * d * d;
    d = xv1.z - xv1.y * xv1.y;  acc += bv1.y * d * d;
    d = xv1.w - xv1.z * xv1.z;  acc += bv1.z * d * d;
    d = xv2.x - xv1.w * xv1.w;  acc += bv1.w * d * d;
    d = xv2.y - xv2.x * xv2.x;  acc += bv2.x * d * d;
    d = xv2.z - xv2.y * xv2.y;  acc += bv2.y * d * d;
    d = xv2.w - xv2.z * xv2.z;  acc += bv2.z * d * d;
    d = xv3.x - xv2.w * xv2.w;  acc += bv2.w * d * d;
    d = xv3.y - xv3.x * xv3.x;  acc += bv3.x * d * d;
    d = xv3.z - xv3.y * xv3.y;  acc += bv3.y * d * d;
    d = xv3.w - xv3.z * xv3.z;  acc += bv3.z * d * d;
    d = xs    - xv3.w * xv3.w;  acc += bv3.w * d * d;

    // wave-64 + block reduction
    #pragma unroll
    for (int off = 32; off > 0; off >>= 1)
        acc += __shfl_down(acc, off, 64);

    __shared__ float sred[4];
    const int lane = t & 63;
    const int wid  = t >> 6;
    if (lane == 0) sred[wid] = acc;
    __syncthreads();
    if (t == 0)
        partial[r] = sred[0] + sred[1] + sred[2] + sred[3];
}

__global__ __launch_bounds__(256) void rosen_final(const float* __restrict__ partial,
                                                   const float* __restrict__ x,
                                                   const float* __restrict__ a,
                                                   const float* __restrict__ mu,
                                                   float* __restrict__ out)
{
    float acc = 0.0f;
    for (int i = threadIdx.x; i < ROWS; i += 256)
        acc += partial[i];

    #pragma unroll
    for (int off = 32; off > 0; off >>= 1)
        acc += __shfl_down(acc, off, 64);

    __shared__ float sred[4];
    const int lane = threadIdx.x & 63;
    const int wid  = threadIdx.x >> 6;
    if (lane == 0) sred[wid] = acc;
    __syncthreads();
    if (threadIdx.x == 0) {
        float total = sred[0] + sred[1] + sred[2] + sred[3];
        float dd = x[0] - mu[0];
        out[0] = -a[0] * dd * dd - total;
    }
}

extern "C" void kernel_launch(void* const* d_in, const int* in_sizes, int n_in,
                              void* d_out, int out_size, void* d_ws, size_t ws_size,
                              hipStream_t stream) {
    const float* x  = (const float*)d_in[0];
    const float* a  = (const float*)d_in[1];
    const float* b  = (const float*)d_in[2];
    const float* mu = (const float*)d_in[3];
    float* out     = (float*)d_out;
    float* partial = (float*)d_ws;   // ROWS floats = 32.8 KB scratch

    rosen_partial<<<ROWS, BLOCK, 0, stream>>>(x, b, partial);
    rosen_final<<<1, 256, 0, stream>>>(partial, x, a, mu, out);
}

// Round 5
// 281.717 us; speedup vs baseline: 1.0105x; 1.0105x over previous
//
#include <hip/hip_runtime.h>

// N1=4097, N2=8192. y[r,c] = x[r*4096 + c + 1]
// sum over r in [0,8191), c in [0,4095):
//   b[r,c] * (y[r,c] - prev^2)^2 ,  prev = y[r,c-1] (c>0) else y[r,4095]
// out = -a*(x[0]-mu)^2 - sum
//
// Round-5: async-DMA staging (global_load_lds), double-buffered, counted
// vmcnt, raw s_barrier. Evidence r1-r4: time is invariant (~96-104us)
// across all VGPR-load structures AND invariant to L3-warm vs cold ->
// per-CU outstanding-read-line cap (~100 lines x 64B / ~600ns ~= 11 GB/s/CU
// = the observed 2.78 TB/s). This round swaps the request path: DMA-to-LDS
// has no VGPR writeback and (hypothesis) a deeper outstanding queue.
// x tile is staged shifted by +1 (tile[c] = y[r,c]) so the col-0 wrap is
// just tile[(c-1) & 4095].

#define ROWS   8191
#define GRID   512
#define BLOCK  256
#define RPB    16          // rows per block (last block: 15)

#define GLDS4(gp, lp)  __builtin_amdgcn_global_load_lds(                     \
    (const __attribute__((address_space(1))) void*)(gp),                     \
    (__attribute__((address_space(3))) void*)(lp), 4, 0, 0)
#define GLDS16(gp, lp) __builtin_amdgcn_global_load_lds(                     \
    (const __attribute__((address_space(1))) void*)(gp),                     \
    (__attribute__((address_space(3))) void*)(lp), 16, 0, 0)

__global__ __launch_bounds__(BLOCK) void rosen_partial(
    const float* __restrict__ x, const float* __restrict__ b,
    float* __restrict__ partial)
{
    __shared__ float sx[2][4096];   // x tile: sx[buf][c] = y[r, c]
    __shared__ float sb[2][4096];   // b tile: sb[buf][c] = b[r, c]

    const unsigned t    = threadIdx.x;
    const unsigned lane = t & 63u;
    const unsigned w    = t >> 6;                 // wave 0..3
    const unsigned row0 = blockIdx.x * RPB;
    const int nrows     = (row0 + RPB <= ROWS) ? RPB : (int)(ROWS - row0);

    // ---- stage(row, buf): 20 DMA instrs per wave, uniform across waves ----
    auto stage = [&](int rr, int buf) {
        const size_t rowbase = (size_t)(row0 + rr) * 4096u;
        // x: 4096 floats starting at rowbase+1 (4B-aligned only -> width 4)
        const float* xs = x + rowbase + 1 + w * 1024u + lane;
        float*       xd = &sx[buf][w * 1024u];
        #pragma unroll
        for (int j = 0; j < 16; ++j)
            GLDS4(xs + j * 64, xd + j * 64);
        // b: 4096 floats at rowbase (16B-aligned -> width 16)
        const float* bs = b + rowbase + w * 1024u + lane * 4u;
        float*       bd = &sb[buf][w * 1024u];
        #pragma unroll
        for (int j = 0; j < 4; ++j)
            GLDS16(bs + j * 256, bd + j * 256);
    };

    float acc = 0.0f;
    stage(0, 0);

    for (int rr = 0; rr < nrows; ++rr) {
        const int cur = rr & 1;
        if (rr + 1 < nrows) {
            stage(rr + 1, cur ^ 1);
            // wait for tile rr (oldest 20) only; tile rr+1 stays in flight
            asm volatile("s_waitcnt vmcnt(20)" ::: "memory");
        } else {
            asm volatile("s_waitcnt vmcnt(0)" ::: "memory");
        }
        __builtin_amdgcn_s_barrier();          // all waves' portions landed

        const float* xt = sx[cur];
        const float* bt = sb[cur];
        #pragma unroll
        for (int k = 0; k < 4; ++k) {
            const unsigned cb = w * 1024u + k * 256u;   // chunk col base
            float4 v  = *(const float4*)(xt + cb + 4u * lane);
            float4 bv = *(const float4*)(bt + cb + 4u * lane);
            float  pu = xt[(cb - 1u) & 4095u];  // uniform broadcast; wraps at cb=0
            float  p  = __shfl_up(v.w, 1, 64);
            if (lane == 0) p = pu;
            if (t == BLOCK - 1 && k == 3) bv.w = 0.0f;   // col 4095 excluded
            float d;
            d = v.x - p   * p;    acc += bv.x * d * d;
            d = v.y - v.x * v.x;  acc += bv.y * d * d;
            d = v.z - v.y * v.y;  acc += bv.z * d * d;
            d = v.w - v.z * v.z;  acc += bv.w * d * d;
        }
        __builtin_amdgcn_s_barrier();          // buf[cur] free for reuse
    }

    // ---- wave-64 + block reduction ----
    #pragma unroll
    for (int off = 32; off > 0; off >>= 1)
        acc += __shfl_down(acc, off, 64);

    __shared__ float sred[4];
    if (lane == 0) sred[w] = acc;
    __syncthreads();
    if (t == 0)
        partial[blockIdx.x] = sred[0] + sred[1] + sred[2] + sred[3];
}

__global__ __launch_bounds__(256) void rosen_final(const float* __restrict__ partial,
                                                   const float* __restrict__ x,
                                                   const float* __restrict__ a,
                                                   const float* __restrict__ mu,
                                                   float* __restrict__ out)
{
    float acc = 0.0f;
    for (int i = threadIdx.x; i < GRID; i += 256)
        acc += partial[i];

    #pragma unroll
    for (int off = 32; off > 0; off >>= 1)
        acc += __shfl_down(acc, off, 64);

    __shared__ float sred[4];
    const int lane = threadIdx.x & 63;
    const int wid  = threadIdx.x >> 6;
    if (lane == 0) sred[wid] = acc;
    __syncthreads();
    if (threadIdx.x == 0) {
        float total = sred[0] + sred[1] + sred[2] + sred[3];
        float dd = x[0] - mu[0];
        out[0] = -a[0] * dd * dd - total;
    }
}

extern "C" void kernel_launch(void* const* d_in, const int* in_sizes, int n_in,
                              void* d_out, int out_size, void* d_ws, size_t ws_size,
                              hipStream_t stream) {
    const float* x  = (const float*)d_in[0];
    const float* a  = (const float*)d_in[1];
    const float* b  = (const float*)d_in[2];
    const float* mu = (const float*)d_in[3];
    float* out     = (float*)d_out;
    float* partial = (float*)d_ws;   // GRID floats = 2 KB scratch

    rosen_partial<<<GRID, BLOCK, 0, stream>>>(x, b, partial);
    rosen_final<<<1, 256, 0, stream>>>(partial, x, a, mu, out);
}